// Round 1
// baseline (302.232 us; speedup 1.0000x reference)
//
#include <hip/hip_runtime.h>

// RWKV time mixing: LN -> token-shift mix -> 3x low-rank proj (bf16 MFMA GEMM)
// -> chunked linear scan (f32) -> output GEMM (+bias).
// B=4, T=2048, C=2048, R=256.

typedef __attribute__((ext_vector_type(8))) __bf16 bf16x8;
typedef __attribute__((ext_vector_type(4))) float f32x4;

static constexpr int Bb = 4, Tt = 2048, Cc = 2048, Rr = 256;
static constexpr int Mrows = Bb * Tt;      // 8192
static constexpr int NCH = 32, CLEN = 64;  // scan chunking: 32 chunks x 64 steps

__device__ __forceinline__ unsigned short f2bf(float f) {
  union { float f; unsigned u; } a; a.f = f;
  unsigned r = (a.u + 0x7FFFu + ((a.u >> 16) & 1u)) >> 16;  // RNE
  return (unsigned short)r;
}
__device__ __forceinline__ float bf2f(unsigned short h) {
  union { unsigned u; float f; } a; a.u = ((unsigned)h) << 16;
  return a.f;
}

__device__ __forceinline__ void gload16(const void* g, void* l) {
  __builtin_amdgcn_global_load_lds(
      (const __attribute__((address_space(1))) void*)g,
      (__attribute__((address_space(3))) void*)l, 16, 0, 0);
}

// ---------------- weight prep: bf16 convert + transpose, decay tables -------
__global__ void prep_weights(const float* __restrict__ wqa, const float* __restrict__ wka,
                             const float* __restrict__ wva, const float* __restrict__ wqb,
                             const float* __restrict__ wkb, const float* __restrict__ wvb,
                             const float* __restrict__ ow,  const float* __restrict__ td,
                             unsigned short* __restrict__ waT, unsigned short* __restrict__ wbT,
                             unsigned short* __restrict__ owT, float* __restrict__ decay,
                             float* __restrict__ decayL) {
  const int g = blockIdx.x * blockDim.x + threadIdx.x;
  const int stride = gridDim.x * blockDim.x;
  // waT[j][c] = wa_p[c][r], j = p*256 + r   (BT layout for GEMM1, N=768, K=2048)
  for (int i = g; i < 3 * Rr * Cc; i += stride) {
    int c = i & (Cc - 1); int jj = i >> 11; int p = jj >> 8; int r = jj & (Rr - 1);
    const float* w = (p == 0) ? wqa : ((p == 1) ? wka : wva);
    waT[i] = f2bf(w[(size_t)c * Rr + r]);
  }
  // wbT[p][d][r] = wb_p[r][d]   (BT layout for GEMM2, N=2048, K=256)
  for (int i = g; i < 3 * Cc * Rr; i += stride) {
    int r = i & (Rr - 1); int d = (i >> 8) & (Cc - 1); int p = i >> 19;
    const float* w = (p == 0) ? wqb : ((p == 1) ? wkb : wvb);
    wbT[i] = f2bf(w[(size_t)r * Cc + d]);
  }
  // owT[d][c] = out_w[d][c]  (already BT layout for final GEMM)
  for (int i = g; i < Cc * Cc; i += stride) owT[i] = f2bf(ow[i]);
  // decay tables
  for (int i = g; i < Cc; i += stride) {
    float e = expf(td[i]);
    decay[i] = expf(-e);
    decayL[i] = expf(-(float)CLEN * e);
  }
}

// ---------------- LayerNorm stats (mean, rstd) per row ----------------------
__global__ void ln_stats_kernel(const float* __restrict__ x, float* __restrict__ stats) {
  const int row = blockIdx.x;
  const float* xr = x + (size_t)row * Cc;
  float sum = 0.f, sq = 0.f;
  for (int i = threadIdx.x; i < Cc / 4; i += 256) {
    float4 v = ((const float4*)xr)[i];
    sum += v.x + v.y + v.z + v.w;
    sq  += v.x * v.x + v.y * v.y + v.z * v.z + v.w * v.w;
  }
  for (int off = 32; off; off >>= 1) {
    sum += __shfl_down(sum, off);
    sq  += __shfl_down(sq, off);
  }
  __shared__ float s[8];
  if ((threadIdx.x & 63) == 0) { s[(threadIdx.x >> 6) * 2] = sum; s[(threadIdx.x >> 6) * 2 + 1] = sq; }
  __syncthreads();
  if (threadIdx.x == 0) {
    float ts = 0.f, tq = 0.f;
    for (int wv = 0; wv < 4; ++wv) { ts += s[wv * 2]; tq += s[wv * 2 + 1]; }
    float mean = ts * (1.0f / Cc);
    float var  = tq * (1.0f / Cc) - mean * mean;
    stats[row * 2] = mean;
    stats[row * 2 + 1] = rsqrtf(var + 1e-5f);
  }
}

// ---------------- token-shift mix (bf16 out) --------------------------------
__global__ void mix_kernel(const float* __restrict__ x, const float* __restrict__ stats,
                           const float* __restrict__ gamma, const float* __restrict__ beta,
                           unsigned short* __restrict__ mix) {
  const int total4 = Mrows * (Cc / 4);
  for (int i = blockIdx.x * blockDim.x + threadIdx.x; i < total4; i += gridDim.x * blockDim.x) {
    const int c4 = i & (Cc / 4 - 1);
    const int m  = i >> 9;
    const int t  = m & (Tt - 1);
    const float4 xv = ((const float4*)x)[i];
    const float mu = stats[2 * m], rs = stats[2 * m + 1];
    const float4 g  = ((const float4*)gamma)[c4];
    const float4 bb = ((const float4*)beta)[c4];
    float mx = (xv.x - mu) * rs * g.x + bb.x;
    float my = (xv.y - mu) * rs * g.y + bb.y;
    float mz = (xv.z - mu) * rs * g.z + bb.z;
    float mw = (xv.w - mu) * rs * g.w + bb.w;
    if (t > 0) {
      const float4 pv = ((const float4*)x)[i - Cc / 4];
      const float pmu = stats[2 * (m - 1)], prs = stats[2 * (m - 1) + 1];
      mx = 0.5f * (mx + (pv.x - pmu) * prs * g.x + bb.x);
      my = 0.5f * (my + (pv.y - pmu) * prs * g.y + bb.y);
      mz = 0.5f * (mz + (pv.z - pmu) * prs * g.z + bb.z);
      mw = 0.5f * (mw + (pv.w - pmu) * prs * g.w + bb.w);
    } else {
      mx *= 0.5f; my *= 0.5f; mz *= 0.5f; mw *= 0.5f;
    }
    ushort4 o;
    o.x = f2bf(mx); o.y = f2bf(my); o.z = f2bf(mz); o.w = f2bf(mw);
    ((ushort4*)mix)[i] = o;
  }
}

// ---------------- MFMA GEMM: C[m][n] = sum_k A[m][k] * Bt[n][k] (+bias) -----
// A, Bt bf16 row-major; 128x128 tile, BK=64, 4 waves (2x2), 16x16x32 MFMA.
template <bool STORE_BF16, bool ADD_BIAS>
__global__ __launch_bounds__(256, 2) void gemm_tile(
    const unsigned short* __restrict__ A, int lda,
    const unsigned short* __restrict__ Bt, int ldb,
    void* __restrict__ Cout, int ldc, int K,
    const float* __restrict__ bias) {
  __shared__ unsigned short As[128 * 64];
  __shared__ unsigned short Bs[128 * 64];
  const int tid = threadIdx.x;
  const int lane = tid & 63;
  const int w = tid >> 6;
  const int wr = w >> 1, wc = w & 1;
  const int fr = lane & 15, fq = lane >> 4;
  const long n0 = (long)blockIdx.x * 128;
  const long m0 = (long)blockIdx.y * 128;

  f32x4 acc[4][4];
#pragma unroll
  for (int i = 0; i < 4; ++i)
#pragma unroll
    for (int j = 0; j < 4; ++j) acc[i][j] = (f32x4){0.f, 0.f, 0.f, 0.f};

  const int srow = tid >> 3;           // 0..31
  const int scol = (tid & 7) * 8;      // element col within 64
  const unsigned short* Ag = A + (m0 + srow) * (long)lda + scol;
  const unsigned short* Bg = Bt + (n0 + srow) * (long)ldb + scol;

  for (int kt = 0; kt < K; kt += 64) {
#pragma unroll
    for (int r = 0; r < 4; ++r) {
      gload16(Ag + (long)(r * 32) * lda + kt, &As[r * 2048 + tid * 8]);
      gload16(Bg + (long)(r * 32) * ldb + kt, &Bs[r * 2048 + tid * 8]);
    }
    __syncthreads();
#pragma unroll
    for (int kk = 0; kk < 64; kk += 32) {
      bf16x8 af[4], bfr[4];
#pragma unroll
      for (int i = 0; i < 4; ++i) af[i] = *(const bf16x8*)&As[(wr * 64 + i * 16 + fr) * 64 + kk + fq * 8];
#pragma unroll
      for (int j = 0; j < 4; ++j) bfr[j] = *(const bf16x8*)&Bs[(wc * 64 + j * 16 + fr) * 64 + kk + fq * 8];
#pragma unroll
      for (int i = 0; i < 4; ++i)
#pragma unroll
        for (int j = 0; j < 4; ++j)
          acc[i][j] = __builtin_amdgcn_mfma_f32_16x16x32_bf16(af[i], bfr[j], acc[i][j], 0, 0, 0);
    }
    __syncthreads();
  }

#pragma unroll
  for (int j = 0; j < 4; ++j) {
    const long col = n0 + wc * 64 + j * 16 + fr;
    const float bv = ADD_BIAS ? bias[col] : 0.0f;
#pragma unroll
    for (int i = 0; i < 4; ++i) {
      const long row0 = m0 + wr * 64 + i * 16 + fq * 4;
#pragma unroll
      for (int r = 0; r < 4; ++r) {
        float val = acc[i][j][r] + bv;
        if (STORE_BF16)
          ((unsigned short*)Cout)[(row0 + r) * ldc + col] = f2bf(val);
        else
          ((float*)Cout)[(row0 + r) * ldc + col] = val;
      }
    }
  }
}

// ---------------- chunked scan --------------------------------------------
// phase A: per (b, chunk, c): local scan with h=0, store chunk-end state.
__global__ void scan_phaseA(const unsigned short* __restrict__ k, const unsigned short* __restrict__ v,
                            const float* __restrict__ decay, float* __restrict__ hend) {
  const int g = blockIdx.x * 256 + threadIdx.x;   // B*NCH*C threads
  const int c = g & (Cc - 1);
  const int j = (g >> 11) & (NCH - 1);
  const int b = g >> 16;
  const float d = decay[c];
  size_t base = ((size_t)(b * Tt + j * CLEN)) * Cc + c;
  float h = 0.f;
#pragma unroll 8
  for (int s = 0; s < CLEN; ++s) {
    size_t idx = base + (size_t)s * Cc;
    float kv = bf2f(k[idx]) * bf2f(v[idx]);
    h = fmaf(d, h, kv);
  }
  hend[(size_t)(b * NCH + j) * Cc + c] = h;
}

// combine: exclusive scan over chunks -> per-chunk incoming state; also h_final.
__global__ void scan_combine(const float* __restrict__ hend, const float* __restrict__ h0,
                             const float* __restrict__ decayL, float* __restrict__ Hin,
                             float* __restrict__ hfinal) {
  const int g = blockIdx.x * 256 + threadIdx.x;   // B*C threads
  const int c = g & (Cc - 1);
  float H = h0[g];
  const float dl = decayL[c];
  const int b = g >> 11;
  for (int j = 0; j < NCH; ++j) {
    size_t idx = (size_t)(b * NCH + j) * Cc + c;
    Hin[idx] = H;
    H = fmaf(dl, H, hend[idx]);
  }
  hfinal[g] = H;
}

// phase B: redo local scan from true incoming state, emit ys = sigmoid(q) * h.
__global__ void scan_phaseB(const unsigned short* __restrict__ q, const unsigned short* __restrict__ k,
                            const unsigned short* __restrict__ v, const float* __restrict__ decay,
                            const float* __restrict__ Hin, unsigned short* __restrict__ ys) {
  const int g = blockIdx.x * 256 + threadIdx.x;
  const int c = g & (Cc - 1);
  const int j = (g >> 11) & (NCH - 1);
  const int b = g >> 16;
  const float d = decay[c];
  float h = Hin[(size_t)(b * NCH + j) * Cc + c];
  size_t base = ((size_t)(b * Tt + j * CLEN)) * Cc + c;
#pragma unroll 4
  for (int s = 0; s < CLEN; ++s) {
    size_t idx = base + (size_t)s * Cc;
    float kv = bf2f(k[idx]) * bf2f(v[idx]);
    h = fmaf(d, h, kv);
    float qq = bf2f(q[idx]);
    float sg = 1.f / (1.f + expf(-qq));
    ys[idx] = f2bf(sg * h);
  }
}

// ---------------- launch ----------------------------------------------------
extern "C" void kernel_launch(void* const* d_in, const int* in_sizes, int n_in,
                              void* d_out, int out_size, void* d_ws, size_t ws_size,
                              hipStream_t stream) {
  const float* x   = (const float*)d_in[0];
  const float* h0  = (const float*)d_in[1];
  const float* gam = (const float*)d_in[2];
  const float* bet = (const float*)d_in[3];
  const float* wqa = (const float*)d_in[4];
  const float* wqb = (const float*)d_in[5];
  const float* wka = (const float*)d_in[6];
  const float* wkb = (const float*)d_in[7];
  const float* wva = (const float*)d_in[8];
  const float* wvb = (const float*)d_in[9];
  const float* ow  = (const float*)d_in[10];
  const float* ob  = (const float*)d_in[11];
  const float* td  = (const float*)d_in[12];
  float* out = (float*)d_out;

  char* ws = (char*)d_ws;
  // workspace layout (bytes)
  unsigned short* waT   = (unsigned short*)(ws + 0);          //  3,145,728
  unsigned short* wbT   = (unsigned short*)(ws + 3145728);    //  3,145,728
  unsigned short* owT   = (unsigned short*)(ws + 6291456);    //  8,388,608
  float*          decay = (float*)(ws + 14680064);            //      8,192
  float*          decayL= (float*)(ws + 14688256);            //      8,192
  float*          stats = (float*)(ws + 14696448);            //     65,536
  unsigned short* mixb  = (unsigned short*)(ws + 14761984);   // 33,554,432 (reused as ys)
  unsigned short* tmp   = (unsigned short*)(ws + 48316416);   // 12,582,912
  unsigned short* vp    = (unsigned short*)(ws + 60899328);   // 33,554,432
  float*          hend  = (float*)(ws + 94453760);            //  1,048,576
  float*          Hin   = (float*)(ws + 95502336);            //  1,048,576
  // q, k staged in d_out (dead before final GEMM overwrites; h_final disjoint)
  unsigned short* qp = (unsigned short*)d_out;
  unsigned short* kp = qp + (size_t)Mrows * Cc;               // bytes [32M, 64M)
  float* hfinal = out + (size_t)Mrows * Cc;                   // bytes [64M, 64M+32K)
  unsigned short* ysb = mixb;

  prep_weights<<<1024, 256, 0, stream>>>(wqa, wka, wva, wqb, wkb, wvb, ow, td,
                                         waT, wbT, owT, decay, decayL);
  ln_stats_kernel<<<Mrows, 256, 0, stream>>>(x, stats);
  mix_kernel<<<2048, 256, 0, stream>>>(x, stats, gam, bet, mixb);

  // G1: tmp[8192][768] = mix @ [wqa|wka|wva]
  gemm_tile<true, false><<<dim3(768 / 128, Mrows / 128), 256, 0, stream>>>(
      mixb, Cc, waT, Cc, tmp, 768, Cc, nullptr);
  // G2: q/k/v[8192][2048] = tmp_p @ w_b_p
  gemm_tile<true, false><<<dim3(Cc / 128, Mrows / 128), 256, 0, stream>>>(
      tmp + 0, 768, wbT + 0 * Cc * Rr, Rr, qp, Cc, Rr, nullptr);
  gemm_tile<true, false><<<dim3(Cc / 128, Mrows / 128), 256, 0, stream>>>(
      tmp + 256, 768, wbT + 1 * Cc * Rr, Rr, kp, Cc, Rr, nullptr);
  gemm_tile<true, false><<<dim3(Cc / 128, Mrows / 128), 256, 0, stream>>>(
      tmp + 512, 768, wbT + 2 * Cc * Rr, Rr, vp, Cc, Rr, nullptr);

  scan_phaseA<<<(Bb * NCH * Cc) / 256, 256, 0, stream>>>(kp, vp, decay, hend);
  scan_combine<<<(Bb * Cc) / 256, 256, 0, stream>>>(hend, h0, decayL, Hin, hfinal);
  scan_phaseB<<<(Bb * NCH * Cc) / 256, 256, 0, stream>>>(qp, kp, vp, decay, Hin, ysb);

  // Gout: out = ys @ out_w^T + out_b
  gemm_tile<false, true><<<dim3(Cc / 128, Mrows / 128), 256, 0, stream>>>(
      ysb, Cc, owT, Cc, out, Cc, Cc, ob);
}

// Round 2
// 274.386 us; speedup vs baseline: 1.1015x; 1.1015x over previous
//
#include <hip/hip_runtime.h>

// RWKV time mixing: LN -> token-shift mix -> 3x low-rank proj -> chunked scan
// -> output GEMM. B=4, T=2048, C=2048, R=256.
// Round 1: 256x256 / BK=32 / 4-deep-ring pipelined GEMM (counted vmcnt) for
// G2 (grouped qkv) and Gout; XCD swizzle; G1 stays on 128^2 2-phase kernel.

typedef __attribute__((ext_vector_type(8))) __bf16 bf16x8;
typedef __attribute__((ext_vector_type(4))) float f32x4;

static constexpr int Bb = 4, Tt = 2048, Cc = 2048, Rr = 256;
static constexpr int Mrows = Bb * Tt;      // 8192
static constexpr int NCH = 32, CLEN = 64;  // scan chunking

__device__ __forceinline__ unsigned short f2bf(float f) {
  union { float f; unsigned u; } a; a.f = f;
  unsigned r = (a.u + 0x7FFFu + ((a.u >> 16) & 1u)) >> 16;  // RNE
  return (unsigned short)r;
}
__device__ __forceinline__ float bf2f(unsigned short h) {
  union { unsigned u; float f; } a; a.u = ((unsigned)h) << 16;
  return a.f;
}

__device__ __forceinline__ void gload16(const void* g, void* l) {
  __builtin_amdgcn_global_load_lds(
      (const __attribute__((address_space(1))) void*)g,
      (__attribute__((address_space(3))) void*)l, 16, 0, 0);
}

// ---------------- weight prep ----------------------------------------------
__global__ void prep_weights(const float* __restrict__ wqa, const float* __restrict__ wka,
                             const float* __restrict__ wva, const float* __restrict__ wqb,
                             const float* __restrict__ wkb, const float* __restrict__ wvb,
                             const float* __restrict__ ow,  const float* __restrict__ td,
                             unsigned short* __restrict__ waT, unsigned short* __restrict__ wbT,
                             unsigned short* __restrict__ owT, float* __restrict__ decay,
                             float* __restrict__ decayL) {
  const int g = blockIdx.x * blockDim.x + threadIdx.x;
  const int stride = gridDim.x * blockDim.x;
  for (int i = g; i < 3 * Rr * Cc; i += stride) {
    int c = i & (Cc - 1); int jj = i >> 11; int p = jj >> 8; int r = jj & (Rr - 1);
    const float* w = (p == 0) ? wqa : ((p == 1) ? wka : wva);
    waT[i] = f2bf(w[(size_t)c * Rr + r]);
  }
  for (int i = g; i < 3 * Cc * Rr; i += stride) {
    int r = i & (Rr - 1); int d = (i >> 8) & (Cc - 1); int p = i >> 19;
    const float* w = (p == 0) ? wqb : ((p == 1) ? wkb : wvb);
    wbT[i] = f2bf(w[(size_t)r * Cc + d]);
  }
  for (int i = g; i < Cc * Cc; i += stride) owT[i] = f2bf(ow[i]);
  for (int i = g; i < Cc; i += stride) {
    float e = expf(td[i]);
    decay[i] = expf(-e);
    decayL[i] = expf(-(float)CLEN * e);
  }
}

// ---------------- LayerNorm stats ------------------------------------------
__global__ void ln_stats_kernel(const float* __restrict__ x, float* __restrict__ stats) {
  const int row = blockIdx.x;
  const float* xr = x + (size_t)row * Cc;
  float sum = 0.f, sq = 0.f;
  for (int i = threadIdx.x; i < Cc / 4; i += 256) {
    float4 v = ((const float4*)xr)[i];
    sum += v.x + v.y + v.z + v.w;
    sq  += v.x * v.x + v.y * v.y + v.z * v.z + v.w * v.w;
  }
  for (int off = 32; off; off >>= 1) {
    sum += __shfl_down(sum, off);
    sq  += __shfl_down(sq, off);
  }
  __shared__ float s[8];
  if ((threadIdx.x & 63) == 0) { s[(threadIdx.x >> 6) * 2] = sum; s[(threadIdx.x >> 6) * 2 + 1] = sq; }
  __syncthreads();
  if (threadIdx.x == 0) {
    float ts = 0.f, tq = 0.f;
    for (int wv = 0; wv < 4; ++wv) { ts += s[wv * 2]; tq += s[wv * 2 + 1]; }
    float mean = ts * (1.0f / Cc);
    float var  = tq * (1.0f / Cc) - mean * mean;
    stats[row * 2] = mean;
    stats[row * 2 + 1] = rsqrtf(var + 1e-5f);
  }
}

// ---------------- token-shift mix ------------------------------------------
__global__ void mix_kernel(const float* __restrict__ x, const float* __restrict__ stats,
                           const float* __restrict__ gamma, const float* __restrict__ beta,
                           unsigned short* __restrict__ mix) {
  const int total4 = Mrows * (Cc / 4);
  for (int i = blockIdx.x * blockDim.x + threadIdx.x; i < total4; i += gridDim.x * blockDim.x) {
    const int c4 = i & (Cc / 4 - 1);
    const int m  = i >> 9;
    const int t  = m & (Tt - 1);
    const float4 xv = ((const float4*)x)[i];
    const float mu = stats[2 * m], rs = stats[2 * m + 1];
    const float4 g  = ((const float4*)gamma)[c4];
    const float4 bb = ((const float4*)beta)[c4];
    float mx = (xv.x - mu) * rs * g.x + bb.x;
    float my = (xv.y - mu) * rs * g.y + bb.y;
    float mz = (xv.z - mu) * rs * g.z + bb.z;
    float mw = (xv.w - mu) * rs * g.w + bb.w;
    if (t > 0) {
      const float4 pv = ((const float4*)x)[i - Cc / 4];
      const float pmu = stats[2 * (m - 1)], prs = stats[2 * (m - 1) + 1];
      mx = 0.5f * (mx + (pv.x - pmu) * prs * g.x + bb.x);
      my = 0.5f * (my + (pv.y - pmu) * prs * g.y + bb.y);
      mz = 0.5f * (mz + (pv.z - pmu) * prs * g.z + bb.z);
      mw = 0.5f * (mw + (pv.w - pmu) * prs * g.w + bb.w);
    } else {
      mx *= 0.5f; my *= 0.5f; mz *= 0.5f; mw *= 0.5f;
    }
    ushort4 o;
    o.x = f2bf(mx); o.y = f2bf(my); o.z = f2bf(mz); o.w = f2bf(mw);
    ((ushort4*)mix)[i] = o;
  }
}

// ---------------- 128^2 2-phase GEMM (kept for G1, N=768) -------------------
template <bool STORE_BF16, bool ADD_BIAS>
__global__ __launch_bounds__(256, 2) void gemm_tile(
    const unsigned short* __restrict__ A, int lda,
    const unsigned short* __restrict__ Bt, int ldb,
    void* __restrict__ Cout, int ldc, int K,
    const float* __restrict__ bias) {
  __shared__ unsigned short As[128 * 64];
  __shared__ unsigned short Bs[128 * 64];
  const int tid = threadIdx.x;
  const int lane = tid & 63;
  const int w = tid >> 6;
  const int wr = w >> 1, wc = w & 1;
  const int fr = lane & 15, fq = lane >> 4;
  const long n0 = (long)blockIdx.x * 128;
  const long m0 = (long)blockIdx.y * 128;

  f32x4 acc[4][4];
#pragma unroll
  for (int i = 0; i < 4; ++i)
#pragma unroll
    for (int j = 0; j < 4; ++j) acc[i][j] = (f32x4){0.f, 0.f, 0.f, 0.f};

  const int srow = tid >> 3;
  const int scol = (tid & 7) * 8;
  const unsigned short* Ag = A + (m0 + srow) * (long)lda + scol;
  const unsigned short* Bg = Bt + (n0 + srow) * (long)ldb + scol;

  for (int kt = 0; kt < K; kt += 64) {
#pragma unroll
    for (int r = 0; r < 4; ++r) {
      gload16(Ag + (long)(r * 32) * lda + kt, &As[r * 2048 + tid * 8]);
      gload16(Bg + (long)(r * 32) * ldb + kt, &Bs[r * 2048 + tid * 8]);
    }
    __syncthreads();
#pragma unroll
    for (int kk = 0; kk < 64; kk += 32) {
      bf16x8 af[4], bfr[4];
#pragma unroll
      for (int i = 0; i < 4; ++i) af[i] = *(const bf16x8*)&As[(wr * 64 + i * 16 + fr) * 64 + kk + fq * 8];
#pragma unroll
      for (int j = 0; j < 4; ++j) bfr[j] = *(const bf16x8*)&Bs[(wc * 64 + j * 16 + fr) * 64 + kk + fq * 8];
#pragma unroll
      for (int i = 0; i < 4; ++i)
#pragma unroll
        for (int j = 0; j < 4; ++j)
          acc[i][j] = __builtin_amdgcn_mfma_f32_16x16x32_bf16(af[i], bfr[j], acc[i][j], 0, 0, 0);
    }
    __syncthreads();
  }

#pragma unroll
  for (int j = 0; j < 4; ++j) {
    const long col = n0 + wc * 64 + j * 16 + fr;
    const float bv = ADD_BIAS ? bias[col] : 0.0f;
#pragma unroll
    for (int i = 0; i < 4; ++i) {
      const long row0 = m0 + wr * 64 + i * 16 + fq * 4;
#pragma unroll
      for (int r = 0; r < 4; ++r) {
        float val = acc[i][j][r] + bv;
        if (STORE_BF16)
          ((unsigned short*)Cout)[(row0 + r) * ldc + col] = f2bf(val);
        else
          ((float*)Cout)[(row0 + r) * ldc + col] = val;
      }
    }
  }
}

// ---------------- 256^2 BK=32 4-ring pipelined GEMM -------------------------
// 512 threads = 8 waves (2 M x 4 N); wave tile 128x64; acc[8][4] f32x4.
// LDS: 4 ring buffers x (A 256x32 + B 256x32) bf16 = 128 KiB.
// Counted vmcnt(8) at tile boundary (4 loads/thread/tile, 2 tiles in flight).
// Grouped over np problems (p = third grid dim folded into 1D swizzled id).
template <bool STORE_BF16, bool ADD_BIAS>
__global__ __launch_bounds__(512, 2) void gemm_pipe(
    const unsigned short* __restrict__ A0p, long lda, long aStrideP,
    const unsigned short* __restrict__ B0p, long ldb, long bStrideP,
    void* c0, void* c1, void* c2, long ldc, int K,
    const float* __restrict__ bias, int nbx, int nby) {
  __shared__ unsigned short lds[4 * 16384];
  const int tid = threadIdx.x;
  // bijective XCD swizzle (grid % 8 == 0 guaranteed by launch)
  const int nwg = gridDim.x;
  const int id = blockIdx.x;
  const int q = nwg >> 3;
  const int swz = (id & 7) * q + (id >> 3);
  const int per = nbx * nby;
  const int p = swz / per;
  const int r2 = swz - p * per;
  const int mblk = r2 / nbx;
  const int nblk = r2 - mblk * nbx;
  const unsigned short* A  = A0p + (long)p * aStrideP;
  const unsigned short* Bt = B0p + (long)p * bStrideP;
  void* Cout = (p == 0) ? c0 : (p == 1 ? c1 : c2);
  const long m0 = (long)mblk * 256, n0 = (long)nblk * 256;

  const int lane = tid & 63, wid = tid >> 6;
  const int wm = wid >> 2, wn = wid & 3;
  const int fr = lane & 15, fq = lane >> 4;

  // staging: thread covers row srow (and srow+128), 16B at col scolE
  const int srow = tid >> 2;
  const int scolE = (tid & 3) * 8;
  const unsigned short* Ag = A + (m0 + srow) * lda + scolE;
  const unsigned short* Bg = Bt + (n0 + srow) * ldb + scolE;

  const unsigned short* aBase = &lds[(wm * 128 + fr) * 32 + fq * 8];
  const unsigned short* bBase = &lds[8192 + (wn * 64 + fr) * 32 + fq * 8];

  f32x4 acc[8][4];
#pragma unroll
  for (int i = 0; i < 8; ++i)
#pragma unroll
    for (int j = 0; j < 4; ++j) acc[i][j] = (f32x4){0.f, 0.f, 0.f, 0.f};

  const int NT = K >> 5;

  auto stageA = [&](int t) {
    unsigned short* d = &lds[(t & 3) * 16384 + tid * 8];
    const long kt = (long)t * 32;
    gload16(Ag + kt, d);
    gload16(Ag + 128 * lda + kt, d + 4096);
  };
  auto stageB = [&](int t) {
    unsigned short* d = &lds[(t & 3) * 16384 + 8192 + tid * 8];
    const long kt = (long)t * 32;
    gload16(Bg + kt, d);
    gload16(Bg + 128 * ldb + kt, d + 4096);
  };

  // prologue: stage tiles 0,1,2  (12 loads/thread in flight)
  stageA(0); stageB(0);
  stageA(1); stageB(1);
  stageA(2); stageB(2);

  for (int t = 0; t < NT; ++t) {
    const int rem = NT - 1 - t;
    // own loads for tile t landed; then barrier => ALL threads' loads landed
    if (rem >= 2)      asm volatile("s_waitcnt vmcnt(8)" ::: "memory");
    else if (rem == 1) asm volatile("s_waitcnt vmcnt(4)" ::: "memory");
    else               asm volatile("s_waitcnt vmcnt(0)" ::: "memory");
    __builtin_amdgcn_s_barrier();

    const unsigned short* ab = aBase + (t & 3) * 16384;
    const unsigned short* bb = bBase + (t & 3) * 16384;

    // ---- phase 1: B frags + A frags i=0..3, stage A(t+3), 16 MFMA ----
    bf16x8 bf[4];
#pragma unroll
    for (int j = 0; j < 4; ++j) bf[j] = *(const bf16x8*)(bb + j * 512);
    bf16x8 af[4];
#pragma unroll
    for (int i = 0; i < 4; ++i) af[i] = *(const bf16x8*)(ab + i * 512);
    if (t + 3 < NT) stageA(t + 3);
    __builtin_amdgcn_s_barrier();
    __builtin_amdgcn_s_setprio(1);
#pragma unroll
    for (int i = 0; i < 4; ++i)
#pragma unroll
      for (int j = 0; j < 4; ++j)
        acc[i][j] = __builtin_amdgcn_mfma_f32_16x16x32_bf16(af[i], bf[j], acc[i][j], 0, 0, 0);
    __builtin_amdgcn_s_setprio(0);
    __builtin_amdgcn_s_barrier();

    // ---- phase 2: A frags i=4..7, stage B(t+3), 16 MFMA ----
#pragma unroll
    for (int i = 0; i < 4; ++i) af[i] = *(const bf16x8*)(ab + (4 + i) * 512);
    if (t + 3 < NT) stageB(t + 3);
    __builtin_amdgcn_s_barrier();
    __builtin_amdgcn_s_setprio(1);
#pragma unroll
    for (int i = 0; i < 4; ++i)
#pragma unroll
      for (int j = 0; j < 4; ++j)
        acc[4 + i][j] = __builtin_amdgcn_mfma_f32_16x16x32_bf16(af[i], bf[j], acc[4 + i][j], 0, 0, 0);
    __builtin_amdgcn_s_setprio(0);
    // next iteration's top barrier closes this tile
  }

#pragma unroll
  for (int j = 0; j < 4; ++j) {
    const long col = n0 + wn * 64 + j * 16 + fr;
    const float bv = ADD_BIAS ? bias[col] : 0.0f;
#pragma unroll
    for (int i = 0; i < 8; ++i) {
      const long row0 = m0 + wm * 128 + i * 16 + fq * 4;
#pragma unroll
      for (int r = 0; r < 4; ++r) {
        float val = acc[i][j][r] + bv;
        if (STORE_BF16)
          ((unsigned short*)Cout)[(row0 + r) * ldc + col] = f2bf(val);
        else
          ((float*)Cout)[(row0 + r) * ldc + col] = val;
      }
    }
  }
}

// ---------------- chunked scan ---------------------------------------------
__global__ void scan_phaseA(const unsigned short* __restrict__ k, const unsigned short* __restrict__ v,
                            const float* __restrict__ decay, float* __restrict__ hend) {
  const int g = blockIdx.x * 256 + threadIdx.x;
  const int c = g & (Cc - 1);
  const int j = (g >> 11) & (NCH - 1);
  const int b = g >> 16;
  const float d = decay[c];
  size_t base = ((size_t)(b * Tt + j * CLEN)) * Cc + c;
  float h = 0.f;
#pragma unroll 8
  for (int s = 0; s < CLEN; ++s) {
    size_t idx = base + (size_t)s * Cc;
    float kv = bf2f(k[idx]) * bf2f(v[idx]);
    h = fmaf(d, h, kv);
  }
  hend[(size_t)(b * NCH + j) * Cc + c] = h;
}

__global__ void scan_combine(const float* __restrict__ hend, const float* __restrict__ h0,
                             const float* __restrict__ decayL, float* __restrict__ Hin,
                             float* __restrict__ hfinal) {
  const int g = blockIdx.x * 256 + threadIdx.x;
  const int c = g & (Cc - 1);
  float H = h0[g];
  const float dl = decayL[c];
  const int b = g >> 11;
  for (int j = 0; j < NCH; ++j) {
    size_t idx = (size_t)(b * NCH + j) * Cc + c;
    Hin[idx] = H;
    H = fmaf(dl, H, hend[idx]);
  }
  hfinal[g] = H;
}

__global__ void scan_phaseB(const unsigned short* __restrict__ q, const unsigned short* __restrict__ k,
                            const unsigned short* __restrict__ v, const float* __restrict__ decay,
                            const float* __restrict__ Hin, unsigned short* __restrict__ ys) {
  const int g = blockIdx.x * 256 + threadIdx.x;
  const int c = g & (Cc - 1);
  const int j = (g >> 11) & (NCH - 1);
  const int b = g >> 16;
  const float d = decay[c];
  float h = Hin[(size_t)(b * NCH + j) * Cc + c];
  size_t base = ((size_t)(b * Tt + j * CLEN)) * Cc + c;
#pragma unroll 4
  for (int s = 0; s < CLEN; ++s) {
    size_t idx = base + (size_t)s * Cc;
    float kv = bf2f(k[idx]) * bf2f(v[idx]);
    h = fmaf(d, h, kv);
    float qq = bf2f(q[idx]);
    float sg = 1.f / (1.f + expf(-qq));
    ys[idx] = f2bf(sg * h);
  }
}

// ---------------- launch ----------------------------------------------------
extern "C" void kernel_launch(void* const* d_in, const int* in_sizes, int n_in,
                              void* d_out, int out_size, void* d_ws, size_t ws_size,
                              hipStream_t stream) {
  const float* x   = (const float*)d_in[0];
  const float* h0  = (const float*)d_in[1];
  const float* gam = (const float*)d_in[2];
  const float* bet = (const float*)d_in[3];
  const float* wqa = (const float*)d_in[4];
  const float* wqb = (const float*)d_in[5];
  const float* wka = (const float*)d_in[6];
  const float* wkb = (const float*)d_in[7];
  const float* wva = (const float*)d_in[8];
  const float* wvb = (const float*)d_in[9];
  const float* ow  = (const float*)d_in[10];
  const float* ob  = (const float*)d_in[11];
  const float* td  = (const float*)d_in[12];
  float* out = (float*)d_out;

  char* ws = (char*)d_ws;
  unsigned short* waT   = (unsigned short*)(ws + 0);          //  3,145,728
  unsigned short* wbT   = (unsigned short*)(ws + 3145728);    //  3,145,728
  unsigned short* owT   = (unsigned short*)(ws + 6291456);    //  8,388,608
  float*          decay = (float*)(ws + 14680064);
  float*          decayL= (float*)(ws + 14688256);
  float*          stats = (float*)(ws + 14696448);
  unsigned short* mixb  = (unsigned short*)(ws + 14761984);   // 33,554,432 (reused as ys)
  unsigned short* tmp   = (unsigned short*)(ws + 48316416);   // 12,582,912
  unsigned short* vp    = (unsigned short*)(ws + 60899328);   // 33,554,432
  float*          hend  = (float*)(ws + 94453760);
  float*          Hin   = (float*)(ws + 95502336);
  unsigned short* qp = (unsigned short*)d_out;
  unsigned short* kp = qp + (size_t)Mrows * Cc;
  float* hfinal = out + (size_t)Mrows * Cc;
  unsigned short* ysb = mixb;

  prep_weights<<<1024, 256, 0, stream>>>(wqa, wka, wva, wqb, wkb, wvb, ow, td,
                                         waT, wbT, owT, decay, decayL);
  ln_stats_kernel<<<Mrows, 256, 0, stream>>>(x, stats);
  mix_kernel<<<2048, 256, 0, stream>>>(x, stats, gam, bet, mixb);

  // G1: tmp[8192][768] = mix @ [wqa|wka|wva]   (128^2 kernel, N=768)
  gemm_tile<true, false><<<dim3(768 / 128, Mrows / 128), 256, 0, stream>>>(
      mixb, Cc, waT, Cc, tmp, 768, Cc, nullptr);

  // G2 grouped: q/k/v[8192][2048] = tmp_p @ w_b_p   (256^2 pipelined, 768 blocks)
  gemm_pipe<true, false><<<8 * 32 * 3, 512, 0, stream>>>(
      tmp, 768, 256, wbT, Rr, (long)Cc * Rr,
      qp, kp, vp, Cc, Rr, nullptr, 8, 32);

  scan_phaseA<<<(Bb * NCH * Cc) / 256, 256, 0, stream>>>(kp, vp, decay, hend);
  scan_combine<<<(Bb * Cc) / 256, 256, 0, stream>>>(hend, h0, decayL, Hin, hfinal);
  scan_phaseB<<<(Bb * NCH * Cc) / 256, 256, 0, stream>>>(qp, kp, vp, decay, Hin, ysb);

  // Gout: out = ys @ out_w^T + out_b   (256^2 pipelined, 256 blocks)
  gemm_pipe<false, true><<<8 * 32, 512, 0, stream>>>(
      ysb, Cc, 0, owT, Cc, 0,
      out, out, out, Cc, Cc, ob, 8, 32);
}